// Round 1
// baseline (601.276 us; speedup 1.0000x reference)
//
#include <hip/hip_runtime.h>
#include <hip/hip_bf16.h>

#define D_IN  2048
#define D_OUT 2048
#define RNK   64
#define NE    16
#define KTOT  3072   // D_IN + NE*RNK
#define TPB   4      // tokens per block in stage1

typedef __attribute__((ext_vector_type(8))) short bf16x8;
typedef __attribute__((ext_vector_type(4))) float f32x4;

__device__ __forceinline__ void async_ld16(const void* g, void* l) {
    __builtin_amdgcn_global_load_lds(
        (const __attribute__((address_space(1))) void*)g,
        (__attribute__((address_space(3))) void*)l,
        16, 0, 0);
}

// ---------------------------------------------------------------------------
// Kernel 1: build Wc [D_OUT][KTOT] bf16 = [ W_base | B' ] where
// B'[n][e*64+r] = B[e][n][r].  One block per output row n, 384 threads x 8 elems.
// ---------------------------------------------------------------------------
__global__ __launch_bounds__(384) void castw_kernel(
    const float* __restrict__ Wb, const float* __restrict__ Bm,
    __hip_bfloat16* __restrict__ Wc)
{
    const int n = blockIdx.x;
    const int c = threadIdx.x * 8;
    const float* src;
    if (c < D_IN) {
        src = Wb + (size_t)n * D_IN + c;
    } else {
        const int j = c - D_IN;
        const int e = j >> 6, r = j & 63;
        src = Bm + ((size_t)e * D_OUT + n) * RNK + r;
    }
    const float4 a = *(const float4*)src;
    const float4 b = *(const float4*)(src + 4);
    const float vv[8] = {a.x, a.y, a.z, a.w, b.x, b.y, b.z, b.w};
    union { bf16x8 v; __hip_bfloat16 h[8]; } u;
#pragma unroll
    for (int q = 0; q < 8; ++q) u.h[q] = __float2bfloat16(vv[q]);
    *(bf16x8*)(Wc + (size_t)n * KTOT + c) = u.v;
}

// ---------------------------------------------------------------------------
// Kernel 2: per 4 tokens — fp32 router+reservoir dots, softmax/top-k,
// emit Xc row = [ bf16(x) | t ] with t[e*64+r] = w_e * rh_r.
// ---------------------------------------------------------------------------
__global__ __launch_bounds__(256) void stage1_kernel(
    const float* __restrict__ x, const float* __restrict__ A,
    const float* __restrict__ Wr, const int* __restrict__ topk_p,
    __hip_bfloat16* __restrict__ Xc)
{
    __shared__ float xs[TPB * D_IN];          // 32 KB
    __shared__ float res[TPB][RNK + NE];
    __shared__ float wfin[TPB][NE];
    const int t0 = blockIdx.x * TPB;
    const int tid = threadIdx.x;

    // load 4 x rows into LDS (float4-coalesced)
    const float4* xg = (const float4*)(x + (size_t)t0 * D_IN);
    float4* xs4 = (float4*)xs;
#pragma unroll
    for (int i = 0; i < (TPB * D_IN / 4) / 256; ++i)   // 8 iters
        xs4[tid + i * 256] = xg[tid + i * 256];
    __syncthreads();

    // emit bf16(x) half of Xc
#pragma unroll
    for (int tt = 0; tt < TPB; ++tt) {
        __hip_bfloat16* xcrow = Xc + (size_t)(t0 + tt) * KTOT;
        const int c = tid * 8;
        union { bf16x8 v; __hip_bfloat16 h[8]; } u;
#pragma unroll
        for (int q = 0; q < 8; ++q) u.h[q] = __float2bfloat16(xs[tt * D_IN + c + q]);
        *(bf16x8*)(xcrow + c) = u.v;
    }

    // 80 fp32 dot products (64 A rows + 16 router rows) for 4 tokens.
    // 16 lane-groups of 16; groups within a wave share xs addresses (LDS broadcast).
    const int wave = tid >> 6, lane = tid & 63;
    const int grp = lane >> 4, sub = lane & 15;
#pragma unroll
    for (int pass = 0; pass < 5; ++pass) {
        const int rowid = pass * 16 + wave * 4 + grp;   // 0..79
        const float4* wv = (const float4*)((rowid < RNK)
                              ? (A + (size_t)rowid * D_IN)
                              : (Wr + (size_t)(rowid - RNK) * D_IN));
        float s[TPB] = {0.f, 0.f, 0.f, 0.f};
        for (int it = 0; it < D_IN / 64; ++it) {        // 32 iters
            const float4 b = wv[sub + it * 16];
#pragma unroll
            for (int tt = 0; tt < TPB; ++tt) {
                const float4 a = xs4[tt * (D_IN / 4) + sub + it * 16];
                s[tt] += a.x * b.x + a.y * b.y + a.z * b.z + a.w * b.w;
            }
        }
#pragma unroll
        for (int tt = 0; tt < TPB; ++tt) {
            float v = s[tt];
#pragma unroll
            for (int off = 8; off; off >>= 1) v += __shfl_down(v, off, 16);
            if (sub == 0) res[tt][rowid] = v;
        }
    }
    __syncthreads();

    // softmax + top-k + renorm (serial per token; 4 threads)
    if (tid < TPB) {
        const int tt = tid;
        const int k = topk_p[0];
        float m = -1e30f;
#pragma unroll
        for (int e = 0; e < NE; ++e) m = fmaxf(m, res[tt][RNK + e]);
        float w[NE]; float ssum = 0.f;
#pragma unroll
        for (int e = 0; e < NE; ++e) { w[e] = __expf(res[tt][RNK + e] - m); ssum += w[e]; }
        const float inv = 1.f / ssum;
#pragma unroll
        for (int e = 0; e < NE; ++e) w[e] *= inv;
        if (k > 0 && k < NE) {
            int chosen[NE];
#pragma unroll
            for (int e = 0; e < NE; ++e) chosen[e] = 0;
            float ksum = 0.f;
            for (int it = 0; it < k; ++it) {
                int bi = 0; float bv = -1.f;
                for (int e = 0; e < NE; ++e)
                    if (!chosen[e] && w[e] > bv) { bv = w[e]; bi = e; }
                chosen[bi] = 1; ksum += bv;
            }
            const float rinv = 1.f / (ksum + 1e-6f);
            for (int e = 0; e < NE; ++e) wfin[tt][e] = chosen[e] ? w[e] * rinv : 0.f;
        } else {
            for (int e = 0; e < NE; ++e) wfin[tt][e] = w[e];
        }
    }
    __syncthreads();

    // emit t half of Xc: t[e*64+r] = wfin[e] * rh[r]
#pragma unroll
    for (int tt = 0; tt < TPB; ++tt) {
        __hip_bfloat16* trow = Xc + (size_t)(t0 + tt) * KTOT + D_IN;
        const int i = tid * 4;
        const int e = i >> 6, r = i & 63;
        const float we = wfin[tt][e];
        union { short4 v; __hip_bfloat16 h[4]; } u;
#pragma unroll
        for (int q = 0; q < 4; ++q) u.h[q] = __float2bfloat16(we * res[tt][r + q]);
        *(short4*)(trow + i) = u.v;
    }
}

// ---------------------------------------------------------------------------
// Kernel 3: m97-style bf16 MFMA GEMM.  C[M][N] = Xc[M][KTOT] @ Wc[N][KTOT]^T + bias.
// 128x128 tile, BK=64, 4 waves each computing 64x64 via 4x4 of 16x16x32 MFMA.
// global_load_lds width=16 staging (wave-uniform LDS base + lane*16).
// ---------------------------------------------------------------------------
__global__ __launch_bounds__(256) void gemm_kernel(
    const __hip_bfloat16* __restrict__ Am,  // [M][KTOT]
    const __hip_bfloat16* __restrict__ Bm,  // [N][KTOT]  (B^T layout)
    const float* __restrict__ bias,         // [N]
    float* __restrict__ C, int M, int N)
{
    __shared__ __hip_bfloat16 lds_a[128 * 64];   // 16 KB
    __shared__ __hip_bfloat16 lds_b[128 * 64];   // 16 KB
    const int tid = threadIdx.x;
    const int wave = tid >> 6, lane = tid & 63;
    const int bm = blockIdx.x, bn = blockIdx.y;
    const int qm = lane & 15, quad = lane >> 4;
    const int ar = lane >> 3;        // row within 8-row staging chunk
    const int ac = (lane & 7) * 8;   // col (bf16 elems) within row

    f32x4 acc[4][4] = {};
    const int wm = (wave >> 1) * 64, wn = (wave & 1) * 64;

    for (int k0 = 0; k0 < KTOT; k0 += 64) {
#pragma unroll
        for (int j = 0; j < 4; ++j) {
            const __hip_bfloat16* ga =
                Am + (size_t)(bm * 128 + wave * 32 + j * 8 + ar) * KTOT + k0 + ac;
            async_ld16(ga, (void*)&lds_a[(wave * 4 + j) * 512]);
            const __hip_bfloat16* gb =
                Bm + (size_t)(bn * 128 + wave * 32 + j * 8 + ar) * KTOT + k0 + ac;
            async_ld16(gb, (void*)&lds_b[(wave * 4 + j) * 512]);
        }
        __syncthreads();   // compiler inserts vmcnt(0) drain before barrier

#pragma unroll
        for (int kk = 0; kk < 64; kk += 32) {
            bf16x8 af[4], bf[4];
#pragma unroll
            for (int i = 0; i < 4; ++i)
                af[i] = *(const bf16x8*)&lds_a[(wm + i * 16 + qm) * 64 + kk + quad * 8];
#pragma unroll
            for (int j = 0; j < 4; ++j)
                bf[j] = *(const bf16x8*)&lds_b[(wn + j * 16 + qm) * 64 + kk + quad * 8];
#pragma unroll
            for (int i = 0; i < 4; ++i)
#pragma unroll
                for (int j = 0; j < 4; ++j)
                    acc[i][j] = __builtin_amdgcn_mfma_f32_16x16x32_bf16(
                        af[i], bf[j], acc[i][j], 0, 0, 0);
        }
        __syncthreads();
    }

    // epilogue: C/D layout col=lane&15, row=quad*4+reg
    const size_t row0 = (size_t)bm * 128 + wm;
    const int col0 = bn * 128 + wn;
#pragma unroll
    for (int j = 0; j < 4; ++j) {
        const int col = col0 + j * 16 + qm;
        const float bb = bias[col];
#pragma unroll
        for (int i = 0; i < 4; ++i) {
#pragma unroll
            for (int r = 0; r < 4; ++r) {
                const size_t row = row0 + i * 16 + quad * 4 + r;
                C[row * (size_t)N + col] = acc[i][j][r] + bb;
            }
        }
    }
}

extern "C" void kernel_launch(void* const* d_in, const int* in_sizes, int n_in,
                              void* d_out, int out_size, void* d_ws, size_t ws_size,
                              hipStream_t stream) {
    const float* x    = (const float*)d_in[0];
    const float* Wb   = (const float*)d_in[1];
    const float* bb   = (const float*)d_in[2];
    const float* A    = (const float*)d_in[3];
    const float* Bm   = (const float*)d_in[4];
    const float* Wr   = (const float*)d_in[5];
    const int*   topk = (const int*)d_in[6];
    float* out = (float*)d_out;
    const int T = in_sizes[0] / D_IN;   // 8192 tokens

    __hip_bfloat16* Xc = (__hip_bfloat16*)d_ws;                               // T*KTOT bf16 (48 MiB)
    __hip_bfloat16* Wc = (__hip_bfloat16*)((char*)d_ws + (size_t)T * KTOT * 2); // D_OUT*KTOT bf16 (12 MiB)

    castw_kernel<<<D_OUT, 384, 0, stream>>>(Wb, Bm, Wc);
    stage1_kernel<<<T / TPB, 256, 0, stream>>>(x, A, Wr, topk, Xc);
    gemm_kernel<<<dim3(T / 128, D_OUT / 128), 256, 0, stream>>>(Xc, Wc, bb, out, T, D_OUT);
}

// Round 2
// 444.754 us; speedup vs baseline: 1.3519x; 1.3519x over previous
//
#include <hip/hip_runtime.h>
#include <hip/hip_bf16.h>

#define D_IN  2048
#define D_OUT 2048
#define RNK   64
#define NE    16
#define KTOT  3072   // D_IN + NE*RNK
#define TPB   8      // tokens per block in router/combine

typedef __attribute__((ext_vector_type(8))) short bf16x8;
typedef __attribute__((ext_vector_type(4))) float f32x4;

__device__ __forceinline__ void async_ld16(const void* g, void* l) {
    __builtin_amdgcn_global_load_lds(
        (const __attribute__((address_space(1))) void*)g,
        (__attribute__((address_space(3))) void*)l,
        16, 0, 0);
}

// ---------------------------------------------------------------------------
// K1: build Wc [D_OUT][KTOT] bf16 = [ W_base | B' ], B'[n][e*64+r] = B[e][n][r]
// ---------------------------------------------------------------------------
__global__ __launch_bounds__(384) void castw_kernel(
    const float* __restrict__ Wb, const float* __restrict__ Bm,
    __hip_bfloat16* __restrict__ Wc)
{
    const int n = blockIdx.x;
    const int c = threadIdx.x * 8;
    const float* src;
    if (c < D_IN) {
        src = Wb + (size_t)n * D_IN + c;
    } else {
        const int j = c - D_IN;
        const int e = j >> 6, r = j & 63;
        src = Bm + ((size_t)e * D_OUT + n) * RNK + r;
    }
    const float4 a = *(const float4*)src;
    const float4 b = *(const float4*)(src + 4);
    const float vv[8] = {a.x, a.y, a.z, a.w, b.x, b.y, b.z, b.w};
    union { bf16x8 v; __hip_bfloat16 h[8]; } u;
#pragma unroll
    for (int q = 0; q < 8; ++q) u.h[q] = __float2bfloat16(vv[q]);
    *(bf16x8*)(Wc + (size_t)n * KTOT + c) = u.v;
}

// ---------------------------------------------------------------------------
// K1b: cast A [RNK][D_IN] fp32 -> bf16 (parked in d_out; consumed before the
// final GEMM overwrites d_out)
// ---------------------------------------------------------------------------
__global__ __launch_bounds__(256) void casta_kernel(
    const float* __restrict__ A, __hip_bfloat16* __restrict__ Ab)
{
    const int r = blockIdx.x;
    const int c = threadIdx.x * 8;
    const float4 a = *(const float4*)(A + (size_t)r * D_IN + c);
    const float4 b = *(const float4*)(A + (size_t)r * D_IN + c + 4);
    const float vv[8] = {a.x, a.y, a.z, a.w, b.x, b.y, b.z, b.w};
    union { bf16x8 v; __hip_bfloat16 h[8]; } u;
#pragma unroll
    for (int q = 0; q < 8; ++q) u.h[q] = __float2bfloat16(vv[q]);
    *(bf16x8*)(Ab + (size_t)r * D_IN + c) = u.v;
}

// ---------------------------------------------------------------------------
// K2: per 8 tokens — emit bf16(x) into Xc x-half; fp32 router logits (16 dots),
// softmax + top-k; write wfin[16] fp32 into the tail of Xc's t-region.
// ---------------------------------------------------------------------------
__global__ __launch_bounds__(256) void router_kernel(
    const float* __restrict__ x, const float* __restrict__ Wr,
    const int* __restrict__ topk_p, __hip_bfloat16* Xc)
{
    __shared__ float xs[TPB * 2052];        // float4 stride 513 (pad kills conflicts)
    __shared__ float part[128];
    __shared__ float logits[TPB][NE];
    const int t0 = blockIdx.x * TPB;
    const int tid = threadIdx.x;

    float4* xs4 = (float4*)xs;
    const float4* xg = (const float4*)(x + (size_t)t0 * D_IN);
#pragma unroll
    for (int tt = 0; tt < TPB; ++tt) {
        xs4[tt * 513 + tid]       = xg[tt * 512 + tid];
        xs4[tt * 513 + tid + 256] = xg[tt * 512 + tid + 256];
    }
    __syncthreads();

    // bf16 x-half emit
#pragma unroll
    for (int tt = 0; tt < TPB; ++tt) {
        const float4 a = xs4[tt * 513 + tid * 2];
        const float4 b = xs4[tt * 513 + tid * 2 + 1];
        const float vv[8] = {a.x, a.y, a.z, a.w, b.x, b.y, b.z, b.w};
        union { bf16x8 v; __hip_bfloat16 h[8]; } u;
#pragma unroll
        for (int q = 0; q < 8; ++q) u.h[q] = __float2bfloat16(vv[q]);
        *(bf16x8*)(Xc + (size_t)(t0 + tt) * KTOT + tid * 8) = u.v;
    }

    // 16 fp32 router dots per token; 2 threads per (token, expert)
    const int e = tid & 15, tok = (tid >> 4) & 7, half = tid >> 7;
    const float4* wr4 = (const float4*)(Wr + (size_t)e * D_IN) + half * 256;
    const float4* xa = &xs4[tok * 513 + half * 256];
    float acc = 0.f;
#pragma unroll 8
    for (int it = 0; it < 256; ++it) {
        const float4 bb = wr4[it];
        const float4 aa = xa[it];
        acc += aa.x * bb.x + aa.y * bb.y + aa.z * bb.z + aa.w * bb.w;
    }
    if (half) part[tid - 128] = acc;
    __syncthreads();
    if (!half) logits[tok][e] = acc + part[tid];
    __syncthreads();

    if (tid < TPB) {
        const int tt = tid;
        const int k = topk_p[0];
        float m = -1e30f;
#pragma unroll
        for (int q = 0; q < NE; ++q) m = fmaxf(m, logits[tt][q]);
        float w[NE]; float ssum = 0.f;
#pragma unroll
        for (int q = 0; q < NE; ++q) { w[q] = __expf(logits[tt][q] - m); ssum += w[q]; }
        const float inv = 1.f / ssum;
#pragma unroll
        for (int q = 0; q < NE; ++q) w[q] *= inv;
        float* wfout = (float*)(Xc + (size_t)(t0 + tt) * KTOT + D_IN + 64);
        if (k > 0 && k < NE) {
            int chosen[NE];
#pragma unroll
            for (int q = 0; q < NE; ++q) chosen[q] = 0;
            float ksum = 0.f;
            for (int it = 0; it < k; ++it) {
                int bi = 0; float bv = -1.f;
                for (int q = 0; q < NE; ++q)
                    if (!chosen[q] && w[q] > bv) { bv = w[q]; bi = q; }
                chosen[bi] = 1; ksum += bv;
            }
            const float rinv = 1.f / (ksum + 1e-6f);
            for (int q = 0; q < NE; ++q) wfout[q] = chosen[q] ? w[q] * rinv : 0.f;
        } else {
            for (int q = 0; q < NE; ++q) wfout[q] = w[q];
        }
    }
}

// ---------------------------------------------------------------------------
// K3: RH = Xc(x-half) @ Ab^T   (M=8192, N=64, K=2048) via MFMA; rh stored bf16
// into Xc row offset [D_IN, D_IN+64) — later overwritten by combine.
// 128x64 tile per block; 4 waves each 32x64 (2x4 of 16x16x32).
// ---------------------------------------------------------------------------
__global__ __launch_bounds__(256) void rhgemm_kernel(
    __hip_bfloat16* Xc, const __hip_bfloat16* __restrict__ Ab)
{
    __shared__ __hip_bfloat16 lds_a[128 * 64];   // 16 KB
    __shared__ __hip_bfloat16 lds_b[64 * 64];    // 8 KB
    const int tid = threadIdx.x;
    const int wave = tid >> 6, lane = tid & 63;
    const int bm = blockIdx.x;
    const int qm = lane & 15, quad = lane >> 4;
    const int ar = lane >> 3;
    const int ac = (lane & 7) * 8;

    f32x4 acc[2][4] = {};

    for (int k0 = 0; k0 < D_IN; k0 += 64) {
#pragma unroll
        for (int j = 0; j < 4; ++j) {
            const __hip_bfloat16* ga =
                Xc + (size_t)(bm * 128 + wave * 32 + j * 8 + ar) * KTOT + k0 + ac;
            async_ld16(ga, (void*)&lds_a[(wave * 4 + j) * 512]);
        }
#pragma unroll
        for (int j = 0; j < 2; ++j) {
            const __hip_bfloat16* gb =
                Ab + (size_t)(wave * 16 + j * 8 + ar) * D_IN + k0 + ac;
            async_ld16(gb, (void*)&lds_b[(wave * 2 + j) * 512]);
        }
        __syncthreads();

#pragma unroll
        for (int kk = 0; kk < 64; kk += 32) {
            bf16x8 af[2], bfr[4];
#pragma unroll
            for (int i = 0; i < 2; ++i)
                af[i] = *(const bf16x8*)&lds_a[(wave * 32 + i * 16 + qm) * 64 + kk + quad * 8];
#pragma unroll
            for (int j = 0; j < 4; ++j)
                bfr[j] = *(const bf16x8*)&lds_b[(j * 16 + qm) * 64 + kk + quad * 8];
#pragma unroll
            for (int i = 0; i < 2; ++i)
#pragma unroll
                for (int j = 0; j < 4; ++j)
                    acc[i][j] = __builtin_amdgcn_mfma_f32_16x16x32_bf16(
                        af[i], bfr[j], acc[i][j], 0, 0, 0);
        }
        __syncthreads();
    }

    const size_t row0 = (size_t)bm * 128 + wave * 32;
#pragma unroll
    for (int j = 0; j < 4; ++j) {
        const int col = j * 16 + qm;
#pragma unroll
        for (int i = 0; i < 2; ++i)
#pragma unroll
            for (int r = 0; r < 4; ++r) {
                const size_t row = row0 + i * 16 + quad * 4 + r;
                Xc[row * KTOT + D_IN + col] = __float2bfloat16(acc[i][j][r]);
            }
    }
}

// ---------------------------------------------------------------------------
// K4: expand t-half: t[e*64+r] = wfin[e] * rh[r] (reads rh/wfin from the same
// region into LDS first, then overwrites it with the full t vector)
// ---------------------------------------------------------------------------
__global__ __launch_bounds__(256) void combine_kernel(__hip_bfloat16* Xc)
{
    __shared__ float rh_s[TPB][RNK];
    __shared__ float wf_s[TPB][NE];
    const int t0 = blockIdx.x * TPB;
    const int tid = threadIdx.x;

#pragma unroll
    for (int rep = 0; rep < 2; ++rep) {
        const int j = tid + rep * 256;
        const int tt = j >> 6, r = j & 63;
        rh_s[tt][r] = __bfloat162float(Xc[(size_t)(t0 + tt) * KTOT + D_IN + r]);
    }
    if (tid < TPB * NE) {
        const int tt = tid >> 4, e = tid & 15;
        wf_s[tt][e] = ((const float*)(Xc + (size_t)(t0 + tt) * KTOT + D_IN + 64))[e];
    }
    __syncthreads();

#pragma unroll
    for (int tt = 0; tt < TPB; ++tt) {
        const int i = tid * 4;
        const int e = i >> 6, r = i & 63;
        const float w = wf_s[tt][e];
        union { short4 v; __hip_bfloat16 h[4]; } u;
#pragma unroll
        for (int q = 0; q < 4; ++q) u.h[q] = __float2bfloat16(w * rh_s[tt][r + q]);
        *(short4*)(Xc + (size_t)(t0 + tt) * KTOT + D_IN + i) = u.v;
    }
}

// ---------------------------------------------------------------------------
// K5: main GEMM C = Xc @ Wc^T + bias (M=8192, N=2048, K=3072), m97-style.
// ---------------------------------------------------------------------------
__global__ __launch_bounds__(256) void gemm_kernel(
    const __hip_bfloat16* __restrict__ Am,
    const __hip_bfloat16* __restrict__ Bm,
    const float* __restrict__ bias,
    float* __restrict__ C, int M, int N)
{
    __shared__ __hip_bfloat16 lds_a[128 * 64];
    __shared__ __hip_bfloat16 lds_b[128 * 64];
    const int tid = threadIdx.x;
    const int wave = tid >> 6, lane = tid & 63;
    const int bm = blockIdx.x, bn = blockIdx.y;
    const int qm = lane & 15, quad = lane >> 4;
    const int ar = lane >> 3;
    const int ac = (lane & 7) * 8;

    f32x4 acc[4][4] = {};
    const int wm = (wave >> 1) * 64, wn = (wave & 1) * 64;

    for (int k0 = 0; k0 < KTOT; k0 += 64) {
#pragma unroll
        for (int j = 0; j < 4; ++j) {
            const __hip_bfloat16* ga =
                Am + (size_t)(bm * 128 + wave * 32 + j * 8 + ar) * KTOT + k0 + ac;
            async_ld16(ga, (void*)&lds_a[(wave * 4 + j) * 512]);
            const __hip_bfloat16* gb =
                Bm + (size_t)(bn * 128 + wave * 32 + j * 8 + ar) * KTOT + k0 + ac;
            async_ld16(gb, (void*)&lds_b[(wave * 4 + j) * 512]);
        }
        __syncthreads();

#pragma unroll
        for (int kk = 0; kk < 64; kk += 32) {
            bf16x8 af[4], bfr[4];
#pragma unroll
            for (int i = 0; i < 4; ++i)
                af[i] = *(const bf16x8*)&lds_a[(wm + i * 16 + qm) * 64 + kk + quad * 8];
#pragma unroll
            for (int j = 0; j < 4; ++j)
                bfr[j] = *(const bf16x8*)&lds_b[(wn + j * 16 + qm) * 64 + kk + quad * 8];
#pragma unroll
            for (int i = 0; i < 4; ++i)
#pragma unroll
                for (int j = 0; j < 4; ++j)
                    acc[i][j] = __builtin_amdgcn_mfma_f32_16x16x32_bf16(
                        af[i], bfr[j], acc[i][j], 0, 0, 0);
        }
        __syncthreads();
    }

    const size_t row0 = (size_t)bm * 128 + wm;
    const int col0 = bn * 128 + wn;
#pragma unroll
    for (int j = 0; j < 4; ++j) {
        const int col = col0 + j * 16 + qm;
        const float bb = bias[col];
#pragma unroll
        for (int i = 0; i < 4; ++i) {
#pragma unroll
            for (int r = 0; r < 4; ++r) {
                const size_t row = row0 + i * 16 + quad * 4 + r;
                C[row * (size_t)N + col] = acc[i][j][r] + bb;
            }
        }
    }
}

extern "C" void kernel_launch(void* const* d_in, const int* in_sizes, int n_in,
                              void* d_out, int out_size, void* d_ws, size_t ws_size,
                              hipStream_t stream) {
    const float* x    = (const float*)d_in[0];
    const float* Wb   = (const float*)d_in[1];
    const float* bb   = (const float*)d_in[2];
    const float* A    = (const float*)d_in[3];
    const float* Bm   = (const float*)d_in[4];
    const float* Wr   = (const float*)d_in[5];
    const int*   topk = (const int*)d_in[6];
    float* out = (float*)d_out;
    const int T = in_sizes[0] / D_IN;   // 8192 tokens

    __hip_bfloat16* Xc = (__hip_bfloat16*)d_ws;                                 // T*KTOT bf16
    __hip_bfloat16* Wc = (__hip_bfloat16*)((char*)d_ws + (size_t)T * KTOT * 2); // D_OUT*KTOT bf16
    __hip_bfloat16* Ab = (__hip_bfloat16*)d_out;  // parked in d_out; consumed before final GEMM

    castw_kernel<<<D_OUT, 384, 0, stream>>>(Wb, Bm, Wc);
    casta_kernel<<<RNK, 256, 0, stream>>>(A, Ab);
    router_kernel<<<T / TPB, 256, 0, stream>>>(x, Wr, topk, Xc);
    rhgemm_kernel<<<T / 128, 256, 0, stream>>>(Xc, Ab);
    combine_kernel<<<T / TPB, 256, 0, stream>>>(Xc);
    gemm_kernel<<<dim3(T / 128, D_OUT / 128), 256, 0, stream>>>(Xc, Wc, bb, out, T, D_OUT);
}

// Round 3
// 382.423 us; speedup vs baseline: 1.5723x; 1.1630x over previous
//
#include <hip/hip_runtime.h>
#include <hip/hip_bf16.h>

#define D_IN  2048
#define D_OUT 2048
#define RNK   64
#define NE    16
#define KTOT  3072   // D_IN + NE*RNK

typedef __attribute__((ext_vector_type(8))) short bf16x8;
typedef __attribute__((ext_vector_type(4))) float f32x4;

__device__ __forceinline__ void async_ld16(const void* g, void* l) {
    __builtin_amdgcn_global_load_lds(
        (const __attribute__((address_space(1))) void*)g,
        (__attribute__((address_space(3))) void*)l,
        16, 0, 0);
}

// ---------------------------------------------------------------------------
// K1: build Wc [D_OUT][KTOT] bf16 = [ W_base | B' ], B'[n][e*64+r] = B[e][n][r]
// ---------------------------------------------------------------------------
__global__ __launch_bounds__(384) void castw_kernel(
    const float* __restrict__ Wb, const float* __restrict__ Bm,
    __hip_bfloat16* __restrict__ Wc)
{
    const int n = blockIdx.x;
    const int c = threadIdx.x * 8;
    const float* src;
    if (c < D_IN) {
        src = Wb + (size_t)n * D_IN + c;
    } else {
        const int j = c - D_IN;
        const int e = j >> 6, r = j & 63;
        src = Bm + ((size_t)e * D_OUT + n) * RNK + r;
    }
    const float4 a = *(const float4*)src;
    const float4 b = *(const float4*)(src + 4);
    const float vv[8] = {a.x, a.y, a.z, a.w, b.x, b.y, b.z, b.w};
    union { bf16x8 v; __hip_bfloat16 h[8]; } u;
#pragma unroll
    for (int q = 0; q < 8; ++q) u.h[q] = __float2bfloat16(vv[q]);
    *(bf16x8*)(Wc + (size_t)n * KTOT + c) = u.v;
}

// ---------------------------------------------------------------------------
// K1b: cast A [RNK][D_IN] fp32 -> bf16 (parked in d_out; consumed before the
// final GEMM overwrites d_out)
// ---------------------------------------------------------------------------
__global__ __launch_bounds__(256) void casta_kernel(
    const float* __restrict__ A, __hip_bfloat16* __restrict__ Ab)
{
    const int r = blockIdx.x;
    const int c = threadIdx.x * 8;
    const float4 a = *(const float4*)(A + (size_t)r * D_IN + c);
    const float4 b = *(const float4*)(A + (size_t)r * D_IN + c + 4);
    const float vv[8] = {a.x, a.y, a.z, a.w, b.x, b.y, b.z, b.w};
    union { bf16x8 v; __hip_bfloat16 h[8]; } u;
#pragma unroll
    for (int q = 0; q < 8; ++q) u.h[q] = __float2bfloat16(vv[q]);
    *(bf16x8*)(Ab + (size_t)r * D_IN + c) = u.v;
}

// ---------------------------------------------------------------------------
// K2: prep — bf16(x) emit + fp32 router logits (K-major, coalesced) +
// softmax/top-k -> wfin (fp32) stashed at Xc row offset D_IN+64.
// 16 tokens/block (4 per wave), 512 blocks.
// ---------------------------------------------------------------------------
__global__ __launch_bounds__(256) void prep_kernel(
    const float* __restrict__ x, const float* __restrict__ Wr,
    const int* __restrict__ topk_p, __hip_bfloat16* Xc)
{
    const int tid = threadIdx.x;
    const int wave = tid >> 6, lane = tid & 63;
    const int t0 = blockIdx.x * 16 + wave * 4;   // 4 tokens per wave

    float acc[NE][4];
#pragma unroll
    for (int e = 0; e < NE; ++e)
#pragma unroll
        for (int t = 0; t < 4; ++t) acc[e][t] = 0.f;

    const float4* x4 = (const float4*)x;
    const float4* wr4 = (const float4*)Wr;
#pragma unroll
    for (int i = 0; i < 8; ++i) {               // K chunks of 256 floats
        float4 xv[4];
#pragma unroll
        for (int t = 0; t < 4; ++t) {
            xv[t] = x4[(size_t)(t0 + t) * 512 + i * 64 + lane];
            union { short4 v; __hip_bfloat16 h[4]; } u;
            u.h[0] = __float2bfloat16(xv[t].x); u.h[1] = __float2bfloat16(xv[t].y);
            u.h[2] = __float2bfloat16(xv[t].z); u.h[3] = __float2bfloat16(xv[t].w);
            *(short4*)(Xc + (size_t)(t0 + t) * KTOT + (i * 64 + lane) * 4) = u.v;
        }
#pragma unroll
        for (int e = 0; e < NE; ++e) {
            const float4 wv = wr4[e * 512 + i * 64 + lane];
#pragma unroll
            for (int t = 0; t < 4; ++t)
                acc[e][t] += xv[t].x * wv.x + xv[t].y * wv.y
                           + xv[t].z * wv.z + xv[t].w * wv.w;
        }
    }
    // butterfly-reduce each of the 64 accumulators across the wave
#pragma unroll
    for (int off = 32; off; off >>= 1)
#pragma unroll
        for (int e = 0; e < NE; ++e)
#pragma unroll
            for (int t = 0; t < 4; ++t)
                acc[e][t] += __shfl_xor(acc[e][t], off, 64);

    if (lane < 4) {
        const int tt = lane;
        const int k = topk_p[0];
        float m = -1e30f;
#pragma unroll
        for (int e = 0; e < NE; ++e) m = fmaxf(m, acc[e][tt]);
        float w[NE]; float ssum = 0.f;
#pragma unroll
        for (int e = 0; e < NE; ++e) { w[e] = __expf(acc[e][tt] - m); ssum += w[e]; }
        const float inv = 1.f / ssum;
#pragma unroll
        for (int e = 0; e < NE; ++e) w[e] *= inv;
        float* wfout = (float*)(Xc + (size_t)(t0 + tt) * KTOT + D_IN + 64);
        if (k > 0 && k < NE) {
            int chosen[NE];
#pragma unroll
            for (int e = 0; e < NE; ++e) chosen[e] = 0;
            float ksum = 0.f;
            for (int it = 0; it < k; ++it) {
                int bi = 0; float bv = -1.f;
                for (int e = 0; e < NE; ++e)
                    if (!chosen[e] && w[e] > bv) { bv = w[e]; bi = e; }
                chosen[bi] = 1; ksum += bv;
            }
            const float rinv = 1.f / (ksum + 1e-6f);
            for (int e = 0; e < NE; ++e) wfout[e] = chosen[e] ? w[e] * rinv : 0.f;
        } else {
            for (int e = 0; e < NE; ++e) wfout[e] = w[e];
        }
    }
}

// ---------------------------------------------------------------------------
// K3: rh+combine fused.  64-token tile: RH = bf16x @ Ab^T (K=2048) via MFMA
// (XOR-swizzled LDS), rh kept in LDS, then t[e*64+r] = wfin[e]*rh[r] written
// to Xc's t-region with coalesced bf16x8 stores.  128 blocks.
// ---------------------------------------------------------------------------
__global__ __launch_bounds__(256) void rhfused_kernel(
    __hip_bfloat16* Xc, const __hip_bfloat16* __restrict__ Ab)
{
    __shared__ __align__(16) char smem[20480];
    __hip_bfloat16* lds_a = (__hip_bfloat16*)smem;            // 64x64 bf16 = 8KB
    __hip_bfloat16* lds_b = (__hip_bfloat16*)(smem + 8192);   // 64x64 bf16 = 8KB
    const int tid = threadIdx.x;
    const int wave = tid >> 6, lane = tid & 63;
    const int qm = lane & 15, quad = lane >> 4;
    const int ar = lane >> 3;
    const int ac = ((lane & 7) ^ ar) * 8;      // XOR-swizzled source granule
    const int t0b = blockIdx.x * 64;

    f32x4 acc[4] = {};

    for (int k0 = 0; k0 < D_IN; k0 += 64) {
#pragma unroll
        for (int j = 0; j < 2; ++j) {
            const __hip_bfloat16* ga =
                Xc + (size_t)(t0b + wave * 16 + j * 8 + ar) * KTOT + k0 + ac;
            async_ld16(ga, (void*)&lds_a[(wave * 2 + j) * 512]);
            const __hip_bfloat16* gb =
                Ab + (size_t)(wave * 16 + j * 8 + ar) * D_IN + k0 + ac;
            async_ld16(gb, (void*)&lds_b[(wave * 2 + j) * 512]);
        }
        __syncthreads();
#pragma unroll
        for (int kk = 0; kk < 64; kk += 32) {
            const int cg = (kk >> 3) + quad;
            const int sw = (cg ^ (qm & 7)) * 8;
            bf16x8 af = *(const bf16x8*)&lds_a[(wave * 16 + qm) * 64 + sw];
            bf16x8 bfr[4];
#pragma unroll
            for (int j = 0; j < 4; ++j)
                bfr[j] = *(const bf16x8*)&lds_b[(j * 16 + qm) * 64 + sw];
#pragma unroll
            for (int j = 0; j < 4; ++j)
                acc[j] = __builtin_amdgcn_mfma_f32_16x16x32_bf16(af, bfr[j], acc[j], 0, 0, 0);
        }
        __syncthreads();
    }

    // rh (fp32) into LDS; wfin into LDS; then expand
    float* rh = (float*)smem;                       // 64x64 f32 = 16KB
    float* wf = (float*)(smem + 16384);             // 64x16 f32 = 4KB
#pragma unroll
    for (int j = 0; j < 4; ++j)
#pragma unroll
        for (int r = 0; r < 4; ++r)
            rh[(wave * 16 + quad * 4 + r) * 64 + j * 16 + qm] = acc[j][r];
    {
        const int t = tid >> 2, part = tid & 3;
        const float* src = (const float*)(Xc + (size_t)(t0b + t) * KTOT + D_IN + 64);
        ((float4*)wf)[t * 4 + part] = ((const float4*)src)[part];
    }
    __syncthreads();

#pragma unroll
    for (int it = 0; it < 32; ++it) {
        const int s = it * 256 + tid;      // bf16x8 store index
        const int t = s >> 7;              // 128 chunks per token
        const int chunk = s & 127;
        const int e = chunk >> 3, r0 = (chunk & 7) * 8;
        const float w = wf[t * 16 + e];
        union { bf16x8 v; __hip_bfloat16 h[8]; } u;
#pragma unroll
        for (int q = 0; q < 8; ++q)
            u.h[q] = __float2bfloat16(w * rh[t * 64 + r0 + q]);
        *(bf16x8*)(Xc + (size_t)(t0b + t) * KTOT + D_IN + chunk * 8) = u.v;
    }
}

// ---------------------------------------------------------------------------
// K4: main GEMM C = Xc @ Wc^T + bias (M=8192, N=2048, K=3072).
// 128x128 tile, XOR-swizzled LDS (conflict-free ds_read_b128), bn-fastest grid.
// ---------------------------------------------------------------------------
__global__ __launch_bounds__(256) void gemm_kernel(
    const __hip_bfloat16* __restrict__ Am,
    const __hip_bfloat16* __restrict__ Bm,
    const float* __restrict__ bias,
    float* __restrict__ C, int M, int N)
{
    __shared__ __hip_bfloat16 lds_a[128 * 64];
    __shared__ __hip_bfloat16 lds_b[128 * 64];
    const int tid = threadIdx.x;
    const int wave = tid >> 6, lane = tid & 63;
    const int bn = blockIdx.x, bm = blockIdx.y;    // bn fastest: L2-friendly
    const int qm = lane & 15, quad = lane >> 4;
    const int ar = lane >> 3;
    const int ac = ((lane & 7) ^ ar) * 8;          // XOR-swizzled source granule

    f32x4 acc[4][4] = {};
    const int wm = (wave >> 1) * 64, wn = (wave & 1) * 64;

    for (int k0 = 0; k0 < KTOT; k0 += 64) {
#pragma unroll
        for (int j = 0; j < 4; ++j) {
            const __hip_bfloat16* ga =
                Am + (size_t)(bm * 128 + wave * 32 + j * 8 + ar) * KTOT + k0 + ac;
            async_ld16(ga, (void*)&lds_a[(wave * 4 + j) * 512]);
            const __hip_bfloat16* gb =
                Bm + (size_t)(bn * 128 + wave * 32 + j * 8 + ar) * KTOT + k0 + ac;
            async_ld16(gb, (void*)&lds_b[(wave * 4 + j) * 512]);
        }
        __syncthreads();

#pragma unroll
        for (int kk = 0; kk < 64; kk += 32) {
            const int cg = (kk >> 3) + quad;
            const int sw = (cg ^ (qm & 7)) * 8;
            bf16x8 af[4], bfr[4];
#pragma unroll
            for (int i = 0; i < 4; ++i)
                af[i] = *(const bf16x8*)&lds_a[(wm + i * 16 + qm) * 64 + sw];
#pragma unroll
            for (int j = 0; j < 4; ++j)
                bfr[j] = *(const bf16x8*)&lds_b[(wn + j * 16 + qm) * 64 + sw];
#pragma unroll
            for (int i = 0; i < 4; ++i)
#pragma unroll
                for (int j = 0; j < 4; ++j)
                    acc[i][j] = __builtin_amdgcn_mfma_f32_16x16x32_bf16(
                        af[i], bfr[j], acc[i][j], 0, 0, 0);
        }
        __syncthreads();
    }

    const size_t row0 = (size_t)bm * 128 + wm;
    const int col0 = bn * 128 + wn;
#pragma unroll
    for (int j = 0; j < 4; ++j) {
        const int col = col0 + j * 16 + qm;
        const float bb = bias[col];
#pragma unroll
        for (int i = 0; i < 4; ++i) {
#pragma unroll
            for (int r = 0; r < 4; ++r) {
                const size_t row = row0 + i * 16 + quad * 4 + r;
                C[row * (size_t)N + col] = acc[i][j][r] + bb;
            }
        }
    }
}

extern "C" void kernel_launch(void* const* d_in, const int* in_sizes, int n_in,
                              void* d_out, int out_size, void* d_ws, size_t ws_size,
                              hipStream_t stream) {
    const float* x    = (const float*)d_in[0];
    const float* Wb   = (const float*)d_in[1];
    const float* bb   = (const float*)d_in[2];
    const float* A    = (const float*)d_in[3];
    const float* Bm   = (const float*)d_in[4];
    const float* Wr   = (const float*)d_in[5];
    const int*   topk = (const int*)d_in[6];
    float* out = (float*)d_out;
    const int T = in_sizes[0] / D_IN;   // 8192 tokens

    __hip_bfloat16* Xc = (__hip_bfloat16*)d_ws;                                 // T*KTOT bf16
    __hip_bfloat16* Wc = (__hip_bfloat16*)((char*)d_ws + (size_t)T * KTOT * 2); // D_OUT*KTOT bf16
    __hip_bfloat16* Ab = (__hip_bfloat16*)d_out;  // parked in d_out; consumed before final GEMM

    castw_kernel<<<D_OUT, 384, 0, stream>>>(Wb, Bm, Wc);
    casta_kernel<<<RNK, 256, 0, stream>>>(A, Ab);
    prep_kernel<<<T / 16, 256, 0, stream>>>(x, Wr, topk, Xc);
    rhfused_kernel<<<T / 64, 256, 0, stream>>>(Xc, Ab);
    gemm_kernel<<<dim3(D_OUT / 128, T / 128), 256, 0, stream>>>(Xc, Wc, bb, out, T, D_OUT);
}

// Round 4
// 365.843 us; speedup vs baseline: 1.6435x; 1.0453x over previous
//
#include <hip/hip_runtime.h>
#include <hip/hip_bf16.h>

#define D_IN  2048
#define D_OUT 2048
#define RNK   64
#define NE    16
#define KTOT  3072   // D_IN + NE*RNK

typedef __attribute__((ext_vector_type(8))) short bf16x8;
typedef __attribute__((ext_vector_type(4))) float f32x4;

__device__ __forceinline__ void async_ld16(const void* g, void* l) {
    __builtin_amdgcn_global_load_lds(
        (const __attribute__((address_space(1))) void*)g,
        (__attribute__((address_space(3))) void*)l,
        16, 0, 0);
}

// ---------------------------------------------------------------------------
// K1: merged weight prep.
//  blocks [0,2048):   Wc row n = [ W_base | B' ], B'[n][e*64+r] = B[e][n][r]
//  blocks [2048,2112): Ab row r = bf16(A[r])  (parked in d_out, consumed
//                      by rhfused before the final GEMM overwrites d_out)
// ---------------------------------------------------------------------------
__global__ __launch_bounds__(384) void castwa_kernel(
    const float* __restrict__ Wb, const float* __restrict__ Bm,
    const float* __restrict__ A,
    __hip_bfloat16* __restrict__ Wc, __hip_bfloat16* __restrict__ Ab)
{
    const int c = threadIdx.x * 8;
    const float* src;
    __hip_bfloat16* dst;
    if (blockIdx.x < D_OUT) {
        const int n = blockIdx.x;
        if (c < D_IN) {
            src = Wb + (size_t)n * D_IN + c;
        } else {
            const int j = c - D_IN;
            const int e = j >> 6, r = j & 63;
            src = Bm + ((size_t)e * D_OUT + n) * RNK + r;
        }
        dst = Wc + (size_t)n * KTOT + c;
    } else {
        if (c >= D_IN) return;
        const int r = blockIdx.x - D_OUT;
        src = A + (size_t)r * D_IN + c;
        dst = Ab + (size_t)r * D_IN + c;
    }
    const float4 a = *(const float4*)src;
    const float4 b = *(const float4*)(src + 4);
    const float vv[8] = {a.x, a.y, a.z, a.w, b.x, b.y, b.z, b.w};
    union { bf16x8 v; __hip_bfloat16 h[8]; } u;
#pragma unroll
    for (int q = 0; q < 8; ++q) u.h[q] = __float2bfloat16(vv[q]);
    *(bf16x8*)dst = u.v;
}

// ---------------------------------------------------------------------------
// K2: prep — bf16(x) emit + fp32 router logits (K-major, coalesced) +
// softmax/top-k -> wfin (fp32, parked in d_out + 32MB).
// 16 tokens/block (4 per wave), 512 blocks.
// ---------------------------------------------------------------------------
__global__ __launch_bounds__(256) void prep_kernel(
    const float* __restrict__ x, const float* __restrict__ Wr,
    const int* __restrict__ topk_p, __hip_bfloat16* __restrict__ Xc,
    float* __restrict__ wfin)
{
    const int tid = threadIdx.x;
    const int wave = tid >> 6, lane = tid & 63;
    const int t0 = blockIdx.x * 16 + wave * 4;   // 4 tokens per wave

    float acc[NE][4];
#pragma unroll
    for (int e = 0; e < NE; ++e)
#pragma unroll
        for (int t = 0; t < 4; ++t) acc[e][t] = 0.f;

    const float4* x4 = (const float4*)x;
    const float4* wr4 = (const float4*)Wr;
#pragma unroll
    for (int i = 0; i < 8; ++i) {               // K chunks of 256 floats
        float4 xv[4];
#pragma unroll
        for (int t = 0; t < 4; ++t) {
            xv[t] = x4[(size_t)(t0 + t) * 512 + i * 64 + lane];
            union { short4 v; __hip_bfloat16 h[4]; } u;
            u.h[0] = __float2bfloat16(xv[t].x); u.h[1] = __float2bfloat16(xv[t].y);
            u.h[2] = __float2bfloat16(xv[t].z); u.h[3] = __float2bfloat16(xv[t].w);
            *(short4*)(Xc + (size_t)(t0 + t) * KTOT + (i * 64 + lane) * 4) = u.v;
        }
#pragma unroll
        for (int e = 0; e < NE; ++e) {
            const float4 wv = wr4[e * 512 + i * 64 + lane];
#pragma unroll
            for (int t = 0; t < 4; ++t)
                acc[e][t] += xv[t].x * wv.x + xv[t].y * wv.y
                           + xv[t].z * wv.z + xv[t].w * wv.w;
        }
    }
#pragma unroll
    for (int off = 32; off; off >>= 1)
#pragma unroll
        for (int e = 0; e < NE; ++e)
#pragma unroll
            for (int t = 0; t < 4; ++t)
                acc[e][t] += __shfl_xor(acc[e][t], off, 64);

    if (lane < 4) {
        const int tt = lane;
        const int k = topk_p[0];
        float m = -1e30f;
#pragma unroll
        for (int e = 0; e < NE; ++e) m = fmaxf(m, acc[e][tt]);
        float w[NE]; float ssum = 0.f;
#pragma unroll
        for (int e = 0; e < NE; ++e) { w[e] = __expf(acc[e][tt] - m); ssum += w[e]; }
        const float inv = 1.f / ssum;
#pragma unroll
        for (int e = 0; e < NE; ++e) w[e] *= inv;
        float* wfout = wfin + (size_t)(t0 + tt) * NE;
        if (k > 0 && k < NE) {
            int chosen[NE];
#pragma unroll
            for (int e = 0; e < NE; ++e) chosen[e] = 0;
            float ksum = 0.f;
            for (int it = 0; it < k; ++it) {
                int bi = 0; float bv = -1.f;
                for (int e = 0; e < NE; ++e)
                    if (!chosen[e] && w[e] > bv) { bv = w[e]; bi = e; }
                chosen[bi] = 1; ksum += bv;
            }
            const float rinv = 1.f / (ksum + 1e-6f);
            for (int e = 0; e < NE; ++e) wfout[e] = chosen[e] ? w[e] * rinv : 0.f;
        } else {
            for (int e = 0; e < NE; ++e) wfout[e] = w[e];
        }
    }
}

// ---------------------------------------------------------------------------
// K3: rh+combine fused.  64-token tile: RH = bf16x @ Ab^T (K=2048) via MFMA
// (XOR-swizzled LDS), rh kept in LDS, then t[e*64+r] = wfin[e]*rh[r] written
// to Xc's t-region with coalesced bf16x8 stores.  128 blocks.
// ---------------------------------------------------------------------------
__global__ __launch_bounds__(256) void rhfused_kernel(
    __hip_bfloat16* Xc, const __hip_bfloat16* __restrict__ Ab,
    const float* __restrict__ wfin)
{
    __shared__ __align__(16) char smem[20480];
    __hip_bfloat16* lds_a = (__hip_bfloat16*)smem;            // 64x64 bf16 = 8KB
    __hip_bfloat16* lds_b = (__hip_bfloat16*)(smem + 8192);   // 64x64 bf16 = 8KB
    const int tid = threadIdx.x;
    const int wave = tid >> 6, lane = tid & 63;
    const int qm = lane & 15, quad = lane >> 4;
    const int ar = lane >> 3;
    const int ac = ((lane & 7) ^ ar) * 8;      // XOR-swizzled source granule
    const int t0b = blockIdx.x * 64;

    f32x4 acc[4] = {};

    for (int k0 = 0; k0 < D_IN; k0 += 64) {
#pragma unroll
        for (int j = 0; j < 2; ++j) {
            const __hip_bfloat16* ga =
                Xc + (size_t)(t0b + wave * 16 + j * 8 + ar) * KTOT + k0 + ac;
            async_ld16(ga, (void*)&lds_a[(wave * 2 + j) * 512]);
            const __hip_bfloat16* gb =
                Ab + (size_t)(wave * 16 + j * 8 + ar) * D_IN + k0 + ac;
            async_ld16(gb, (void*)&lds_b[(wave * 2 + j) * 512]);
        }
        __syncthreads();
#pragma unroll
        for (int kk = 0; kk < 64; kk += 32) {
            const int cg = (kk >> 3) + quad;
            const int sw = (cg ^ (qm & 7)) * 8;
            bf16x8 af = *(const bf16x8*)&lds_a[(wave * 16 + qm) * 64 + sw];
            bf16x8 bfr[4];
#pragma unroll
            for (int j = 0; j < 4; ++j)
                bfr[j] = *(const bf16x8*)&lds_b[(j * 16 + qm) * 64 + sw];
#pragma unroll
            for (int j = 0; j < 4; ++j)
                acc[j] = __builtin_amdgcn_mfma_f32_16x16x32_bf16(af, bfr[j], acc[j], 0, 0, 0);
        }
        __syncthreads();
    }

    float* rh = (float*)smem;                       // 64x64 f32 = 16KB
    float* wf = (float*)(smem + 16384);             // 64x16 f32 = 4KB
#pragma unroll
    for (int j = 0; j < 4; ++j)
#pragma unroll
        for (int r = 0; r < 4; ++r)
            rh[(wave * 16 + quad * 4 + r) * 64 + j * 16 + qm] = acc[j][r];
    {
        const int t = tid >> 2, part = tid & 3;
        const float* src = wfin + (size_t)(t0b + t) * NE;
        ((float4*)wf)[t * 4 + part] = ((const float4*)src)[part];
    }
    __syncthreads();

#pragma unroll
    for (int it = 0; it < 32; ++it) {
        const int s = it * 256 + tid;
        const int t = s >> 7;
        const int chunk = s & 127;
        const int e = chunk >> 3, r0 = (chunk & 7) * 8;
        const float w = wf[t * 16 + e];
        union { bf16x8 v; __hip_bfloat16 h[8]; } u;
#pragma unroll
        for (int q = 0; q < 8; ++q)
            u.h[q] = __float2bfloat16(w * rh[t * 64 + r0 + q]);
        *(bf16x8*)(Xc + (size_t)(t0b + t) * KTOT + D_IN + chunk * 8) = u.v;
    }
}

// ---------------------------------------------------------------------------
// K4: main GEMM C = Xc @ Wc^T + bias (M=8192, N=2048, K=3072).
// 128x128 tile, XOR-swizzled LDS, 8x8 grouped block swizzle (L2/L3 reuse),
// hoisted staging pointers.
// ---------------------------------------------------------------------------
__global__ __launch_bounds__(256) void gemm_kernel(
    const __hip_bfloat16* __restrict__ Am,
    const __hip_bfloat16* __restrict__ Bm,
    const float* __restrict__ bias,
    float* __restrict__ C, int M, int N)
{
    __shared__ __hip_bfloat16 lds_a[128 * 64];
    __shared__ __hip_bfloat16 lds_b[128 * 64];
    const int tid = threadIdx.x;
    const int wave = tid >> 6, lane = tid & 63;
    // 8x8 grouped swizzle: supergroup = 8 bm x 8 bn (64 blocks); XCD round-robin
    // (gid & 7) keeps one Wc block-column per XCD L2 within a supergroup.
    const int gid = blockIdx.x;
    const int sid = gid >> 6, w = gid & 63;
    const int bm = (sid >> 1) * 8 + (w >> 3);
    const int bn = (sid & 1) * 8 + (w & 7);
    const int qm = lane & 15, quad = lane >> 4;
    const int ar = lane >> 3;
    const int ac = ((lane & 7) ^ ar) * 8;          // XOR-swizzled source granule

    f32x4 acc[4][4] = {};
    const int wm = (wave >> 1) * 64, wn = (wave & 1) * 64;

    const __hip_bfloat16* ga[4];
    const __hip_bfloat16* gb[4];
#pragma unroll
    for (int j = 0; j < 4; ++j) {
        ga[j] = Am + (size_t)(bm * 128 + wave * 32 + j * 8 + ar) * KTOT + ac;
        gb[j] = Bm + (size_t)(bn * 128 + wave * 32 + j * 8 + ar) * KTOT + ac;
    }

    for (int k0 = 0; k0 < KTOT; k0 += 64) {
#pragma unroll
        for (int j = 0; j < 4; ++j) {
            async_ld16(ga[j], (void*)&lds_a[(wave * 4 + j) * 512]);
            async_ld16(gb[j], (void*)&lds_b[(wave * 4 + j) * 512]);
            ga[j] += 64; gb[j] += 64;
        }
        __syncthreads();

#pragma unroll
        for (int kk = 0; kk < 64; kk += 32) {
            const int cg = (kk >> 3) + quad;
            const int sw = (cg ^ (qm & 7)) * 8;
            bf16x8 af[4], bfr[4];
#pragma unroll
            for (int i = 0; i < 4; ++i)
                af[i] = *(const bf16x8*)&lds_a[(wm + i * 16 + qm) * 64 + sw];
#pragma unroll
            for (int j = 0; j < 4; ++j)
                bfr[j] = *(const bf16x8*)&lds_b[(wn + j * 16 + qm) * 64 + sw];
#pragma unroll
            for (int i = 0; i < 4; ++i)
#pragma unroll
                for (int j = 0; j < 4; ++j)
                    acc[i][j] = __builtin_amdgcn_mfma_f32_16x16x32_bf16(
                        af[i], bfr[j], acc[i][j], 0, 0, 0);
        }
        __syncthreads();
    }

    const size_t row0 = (size_t)bm * 128 + wm;
    const int col0 = bn * 128 + wn;
#pragma unroll
    for (int j = 0; j < 4; ++j) {
        const int col = col0 + j * 16 + qm;
        const float bb = bias[col];
#pragma unroll
        for (int i = 0; i < 4; ++i) {
#pragma unroll
            for (int r = 0; r < 4; ++r) {
                const size_t row = row0 + i * 16 + quad * 4 + r;
                C[row * (size_t)N + col] = acc[i][j][r] + bb;
            }
        }
    }
}

extern "C" void kernel_launch(void* const* d_in, const int* in_sizes, int n_in,
                              void* d_out, int out_size, void* d_ws, size_t ws_size,
                              hipStream_t stream) {
    const float* x    = (const float*)d_in[0];
    const float* Wb   = (const float*)d_in[1];
    const float* bb   = (const float*)d_in[2];
    const float* A    = (const float*)d_in[3];
    const float* Bm   = (const float*)d_in[4];
    const float* Wr   = (const float*)d_in[5];
    const int*   topk = (const int*)d_in[6];
    float* out = (float*)d_out;
    const int T = in_sizes[0] / D_IN;   // 8192 tokens

    __hip_bfloat16* Xc = (__hip_bfloat16*)d_ws;                                 // T*KTOT bf16 (48MB)
    __hip_bfloat16* Wc = (__hip_bfloat16*)((char*)d_ws + (size_t)T * KTOT * 2); // D_OUT*KTOT bf16 (12MB)
    // Parked in d_out (fully overwritten by the final GEMM):
    __hip_bfloat16* Ab = (__hip_bfloat16*)d_out;              // 256 KB at front
    float* wfin = (float*)d_out + 8 * 1024 * 1024;            // 512 KB at +32MB

    castwa_kernel<<<D_OUT + RNK, 384, 0, stream>>>(Wb, Bm, A, Wc, Ab);
    prep_kernel<<<T / 16, 256, 0, stream>>>(x, Wr, topk, Xc, wfin);
    rhfused_kernel<<<T / 64, 256, 0, stream>>>(Xc, Ab, wfin);
    gemm_kernel<<<(T / 128) * (D_OUT / 128), 256, 0, stream>>>(Xc, Wc, bb, out, T, D_OUT);
}

// Round 5
// 362.408 us; speedup vs baseline: 1.6591x; 1.0095x over previous
//
#include <hip/hip_runtime.h>
#include <hip/hip_bf16.h>

#define D_IN  2048
#define D_OUT 2048
#define RNK   64
#define NE    16
#define KTOT  3072   // D_IN + NE*RNK

typedef __attribute__((ext_vector_type(8))) short bf16x8;
typedef __attribute__((ext_vector_type(4))) float f32x4;

__device__ __forceinline__ void async_ld16(const void* g, void* l) {
    __builtin_amdgcn_global_load_lds(
        (const __attribute__((address_space(1))) void*)g,
        (__attribute__((address_space(3))) void*)l,
        16, 0, 0);
}

// ---------------------------------------------------------------------------
// K1: merged weight prep.
//  blocks [0,2048):   Wc row n = [ W_base | B' ], B'[n][e*64+r] = B[e][n][r]
//  blocks [2048,2112): Ab row r = bf16(A[r])  (parked in d_out)
// ---------------------------------------------------------------------------
__global__ __launch_bounds__(384) void castwa_kernel(
    const float* __restrict__ Wb, const float* __restrict__ Bm,
    const float* __restrict__ A,
    __hip_bfloat16* __restrict__ Wc, __hip_bfloat16* __restrict__ Ab)
{
    const int c = threadIdx.x * 8;
    const float* src;
    __hip_bfloat16* dst;
    if (blockIdx.x < D_OUT) {
        const int n = blockIdx.x;
        if (c < D_IN) {
            src = Wb + (size_t)n * D_IN + c;
        } else {
            const int j = c - D_IN;
            const int e = j >> 6, r = j & 63;
            src = Bm + ((size_t)e * D_OUT + n) * RNK + r;
        }
        dst = Wc + (size_t)n * KTOT + c;
    } else {
        if (c >= D_IN) return;
        const int r = blockIdx.x - D_OUT;
        src = A + (size_t)r * D_IN + c;
        dst = Ab + (size_t)r * D_IN + c;
    }
    const float4 a = *(const float4*)src;
    const float4 b = *(const float4*)(src + 4);
    const float vv[8] = {a.x, a.y, a.z, a.w, b.x, b.y, b.z, b.w};
    union { bf16x8 v; __hip_bfloat16 h[8]; } u;
#pragma unroll
    for (int q = 0; q < 8; ++q) u.h[q] = __float2bfloat16(vv[q]);
    *(bf16x8*)dst = u.v;
}

// ---------------------------------------------------------------------------
// K2: prep — bf16(x) emit + fp32 router logits + softmax/top-k -> wfin.
// 8 tokens/block (2 per wave), 1024 blocks: 2x the waves of R4 for L2-latency
// hiding on the 16 Wr loads per K-chunk.
// ---------------------------------------------------------------------------
__global__ __launch_bounds__(256) void prep_kernel(
    const float* __restrict__ x, const float* __restrict__ Wr,
    const int* __restrict__ topk_p, __hip_bfloat16* __restrict__ Xc,
    float* __restrict__ wfin)
{
    const int tid = threadIdx.x;
    const int wave = tid >> 6, lane = tid & 63;
    const int t0 = blockIdx.x * 8 + wave * 2;   // 2 tokens per wave

    float acc[NE][2];
#pragma unroll
    for (int e = 0; e < NE; ++e) { acc[e][0] = 0.f; acc[e][1] = 0.f; }

    const float4* x4 = (const float4*)x;
    const float4* wr4 = (const float4*)Wr;
#pragma unroll
    for (int i = 0; i < 8; ++i) {               // K chunks of 256 floats
        float4 xv[2];
#pragma unroll
        for (int t = 0; t < 2; ++t) {
            xv[t] = x4[(size_t)(t0 + t) * 512 + i * 64 + lane];
            union { short4 v; __hip_bfloat16 h[4]; } u;
            u.h[0] = __float2bfloat16(xv[t].x); u.h[1] = __float2bfloat16(xv[t].y);
            u.h[2] = __float2bfloat16(xv[t].z); u.h[3] = __float2bfloat16(xv[t].w);
            *(short4*)(Xc + (size_t)(t0 + t) * KTOT + (i * 64 + lane) * 4) = u.v;
        }
#pragma unroll
        for (int e = 0; e < NE; ++e) {
            const float4 wv = wr4[e * 512 + i * 64 + lane];
#pragma unroll
            for (int t = 0; t < 2; ++t)
                acc[e][t] += xv[t].x * wv.x + xv[t].y * wv.y
                           + xv[t].z * wv.z + xv[t].w * wv.w;
        }
    }
#pragma unroll
    for (int off = 32; off; off >>= 1)
#pragma unroll
        for (int e = 0; e < NE; ++e)
#pragma unroll
            for (int t = 0; t < 2; ++t)
                acc[e][t] += __shfl_xor(acc[e][t], off, 64);

    if (lane < 2) {
        const int tt = lane;
        const int k = topk_p[0];
        float m = -1e30f;
#pragma unroll
        for (int e = 0; e < NE; ++e) m = fmaxf(m, acc[e][tt]);
        float w[NE]; float ssum = 0.f;
#pragma unroll
        for (int e = 0; e < NE; ++e) { w[e] = __expf(acc[e][tt] - m); ssum += w[e]; }
        const float inv = 1.f / ssum;
#pragma unroll
        for (int e = 0; e < NE; ++e) w[e] *= inv;
        float* wfout = wfin + (size_t)(t0 + tt) * NE;
        if (k > 0 && k < NE) {
            int chosen[NE];
#pragma unroll
            for (int e = 0; e < NE; ++e) chosen[e] = 0;
            float ksum = 0.f;
            for (int it = 0; it < k; ++it) {
                int bi = 0; float bv = -1.f;
                for (int e = 0; e < NE; ++e)
                    if (!chosen[e] && w[e] > bv) { bv = w[e]; bi = e; }
                chosen[bi] = 1; ksum += bv;
            }
            const float rinv = 1.f / (ksum + 1e-6f);
            for (int e = 0; e < NE; ++e) wfout[e] = chosen[e] ? w[e] * rinv : 0.f;
        } else {
            for (int e = 0; e < NE; ++e) wfout[e] = w[e];
        }
    }
}

// ---------------------------------------------------------------------------
// K3: rh+combine fused, 16-token tiles (512 blocks = 2/CU for latency hiding).
// RH = bf16x @ Ab^T (K=2048) via MFMA, XOR-swizzled LDS; then
// t[e*64+r] = wfin[e]*rh[r] written with coalesced bf16x8 stores.
// ---------------------------------------------------------------------------
__global__ __launch_bounds__(256) void rhfused_kernel(
    __hip_bfloat16* Xc, const __hip_bfloat16* __restrict__ Ab,
    const float* __restrict__ wfin)
{
    __shared__ __align__(16) char smem[10240 + 1024];
    __hip_bfloat16* lds_a = (__hip_bfloat16*)smem;            // 16x64 bf16 = 2KB
    __hip_bfloat16* lds_b = (__hip_bfloat16*)(smem + 2048);   // 64x64 bf16 = 8KB
    const int tid = threadIdx.x;
    const int wave = tid >> 6, lane = tid & 63;
    const int qm = lane & 15, quad = lane >> 4;
    const int ar = lane >> 3;
    const int ac = ((lane & 7) ^ ar) * 8;      // XOR-swizzled source granule
    const int t0b = blockIdx.x * 16;

    f32x4 acc = {};

    for (int k0 = 0; k0 < D_IN; k0 += 64) {
        if (wave < 2) {   // A tile: 16 token rows
            const __hip_bfloat16* ga =
                Xc + (size_t)(t0b + wave * 8 + ar) * KTOT + k0 + ac;
            async_ld16(ga, (void*)&lds_a[wave * 512]);
        }
#pragma unroll
        for (int j = 0; j < 2; ++j) {          // B tile: 64 A-rows
            const __hip_bfloat16* gb =
                Ab + (size_t)(wave * 16 + j * 8 + ar) * D_IN + k0 + ac;
            async_ld16(gb, (void*)&lds_b[(wave * 2 + j) * 512]);
        }
        __syncthreads();
#pragma unroll
        for (int kk = 0; kk < 64; kk += 32) {
            const int cg = (kk >> 3) + quad;
            const int sw = (cg ^ (qm & 7)) * 8;
            bf16x8 af = *(const bf16x8*)&lds_a[qm * 64 + sw];
            bf16x8 bfr = *(const bf16x8*)&lds_b[(wave * 16 + qm) * 64 + sw];
            acc = __builtin_amdgcn_mfma_f32_16x16x32_bf16(af, bfr, acc, 0, 0, 0);
        }
        __syncthreads();
    }

    float* rh = (float*)smem;                       // 16x64 f32 = 4KB
    float* wf = (float*)(smem + 4096);              // 16x16 f32 = 1KB
#pragma unroll
    for (int r = 0; r < 4; ++r)
        rh[(quad * 4 + r) * 64 + wave * 16 + qm] = acc[r];   // token row, RH col
    if (tid < 64) {
        const int t = tid >> 2, part = tid & 3;
        ((float4*)wf)[t * 4 + part] =
            ((const float4*)(wfin + (size_t)(t0b + t) * NE))[part];
    }
    __syncthreads();

#pragma unroll
    for (int it = 0; it < 8; ++it) {
        const int s = it * 256 + tid;      // bf16x8 store index
        const int t = s >> 7;              // 128 chunks per token
        const int chunk = s & 127;
        const int e = chunk >> 3, r0 = (chunk & 7) * 8;
        const float w = wf[t * 16 + e];
        union { bf16x8 v; __hip_bfloat16 h[8]; } u;
#pragma unroll
        for (int q = 0; q < 8; ++q)
            u.h[q] = __float2bfloat16(w * rh[t * 64 + r0 + q]);
        *(bf16x8*)(Xc + (size_t)(t0b + t) * KTOT + D_IN + chunk * 8) = u.v;
    }
}

// ---------------------------------------------------------------------------
// K4: main GEMM C = Xc @ Wc^T + bias (M=8192, N=2048, K=3072).
// 128x128 tile, XOR-swizzled LDS, bm-fastest grid (R2's empirically best
// fetch: 99 MB vs 209 MB for bn-fastest/supertile), hoisted staging pointers.
// ---------------------------------------------------------------------------
__global__ __launch_bounds__(256) void gemm_kernel(
    const __hip_bfloat16* __restrict__ Am,
    const __hip_bfloat16* __restrict__ Bm,
    const float* __restrict__ bias,
    float* __restrict__ C, int M, int N)
{
    __shared__ __hip_bfloat16 lds_a[128 * 64];
    __shared__ __hip_bfloat16 lds_b[128 * 64];
    const int tid = threadIdx.x;
    const int wave = tid >> 6, lane = tid & 63;
    const int bm = blockIdx.x, bn = blockIdx.y;    // bm fastest
    const int qm = lane & 15, quad = lane >> 4;
    const int ar = lane >> 3;
    const int ac = ((lane & 7) ^ ar) * 8;          // XOR-swizzled source granule

    f32x4 acc[4][4] = {};
    const int wm = (wave >> 1) * 64, wn = (wave & 1) * 64;

    const __hip_bfloat16* ga[4];
    const __hip_bfloat16* gb[4];
#pragma unroll
    for (int j = 0; j < 4; ++j) {
        ga[j] = Am + (size_t)(bm * 128 + wave * 32 + j * 8 + ar) * KTOT + ac;
        gb[j] = Bm + (size_t)(bn * 128 + wave * 32 + j * 8 + ar) * KTOT + ac;
    }

    for (int k0 = 0; k0 < KTOT; k0 += 64) {
#pragma unroll
        for (int j = 0; j < 4; ++j) {
            async_ld16(ga[j], (void*)&lds_a[(wave * 4 + j) * 512]);
            async_ld16(gb[j], (void*)&lds_b[(wave * 4 + j) * 512]);
            ga[j] += 64; gb[j] += 64;
        }
        __syncthreads();

#pragma unroll
        for (int kk = 0; kk < 64; kk += 32) {
            const int cg = (kk >> 3) + quad;
            const int sw = (cg ^ (qm & 7)) * 8;
            bf16x8 af[4], bfr[4];
#pragma unroll
            for (int i = 0; i < 4; ++i)
                af[i] = *(const bf16x8*)&lds_a[(wm + i * 16 + qm) * 64 + sw];
#pragma unroll
            for (int j = 0; j < 4; ++j)
                bfr[j] = *(const bf16x8*)&lds_b[(wn + j * 16 + qm) * 64 + sw];
#pragma unroll
            for (int i = 0; i < 4; ++i)
#pragma unroll
                for (int j = 0; j < 4; ++j)
                    acc[i][j] = __builtin_amdgcn_mfma_f32_16x16x32_bf16(
                        af[i], bfr[j], acc[i][j], 0, 0, 0);
        }
        __syncthreads();
    }

    const size_t row0 = (size_t)bm * 128 + wm;
    const int col0 = bn * 128 + wn;
#pragma unroll
    for (int j = 0; j < 4; ++j) {
        const int col = col0 + j * 16 + qm;
        const float bb = bias[col];
#pragma unroll
        for (int i = 0; i < 4; ++i) {
#pragma unroll
            for (int r = 0; r < 4; ++r) {
                const size_t row = row0 + i * 16 + quad * 4 + r;
                C[row * (size_t)N + col] = acc[i][j][r] + bb;
            }
        }
    }
}

extern "C" void kernel_launch(void* const* d_in, const int* in_sizes, int n_in,
                              void* d_out, int out_size, void* d_ws, size_t ws_size,
                              hipStream_t stream) {
    const float* x    = (const float*)d_in[0];
    const float* Wb   = (const float*)d_in[1];
    const float* bb   = (const float*)d_in[2];
    const float* A    = (const float*)d_in[3];
    const float* Bm   = (const float*)d_in[4];
    const float* Wr   = (const float*)d_in[5];
    const int*   topk = (const int*)d_in[6];
    float* out = (float*)d_out;
    const int T = in_sizes[0] / D_IN;   // 8192 tokens

    __hip_bfloat16* Xc = (__hip_bfloat16*)d_ws;                                 // T*KTOT bf16 (48MB)
    __hip_bfloat16* Wc = (__hip_bfloat16*)((char*)d_ws + (size_t)T * KTOT * 2); // D_OUT*KTOT bf16 (12MB)
    // Parked in d_out (fully overwritten by the final GEMM):
    __hip_bfloat16* Ab = (__hip_bfloat16*)d_out;              // 256 KB at front
    float* wfin = (float*)d_out + 8 * 1024 * 1024;            // 512 KB at +32MB

    castwa_kernel<<<D_OUT + RNK, 384, 0, stream>>>(Wb, Bm, A, Wc, Ab);
    prep_kernel<<<T / 8, 256, 0, stream>>>(x, Wr, topk, Xc, wfin);
    rhfused_kernel<<<T / 16, 256, 0, stream>>>(Xc, Ab, wfin);
    gemm_kernel<<<dim3(T / 128, D_OUT / 128), 256, 0, stream>>>(Xc, Wc, bb, out, T, D_OUT);
}